// Round 6
// baseline (154.672 us; speedup 1.0000x reference)
//
#include <hip/hip_runtime.h>
#include <math.h>

#define Ddim 384
#define D4 96                      // Ddim/4
#define NUM_ITEMS 16384
#define NUM_CLUSTERS 256
#define MCS 128                    // MAX_CLUSTER_SIZE
#define NEG_INF_F (-1e9f)
#define NTOK 4096
#define TPB 16                     // tokens per cluster block (4 per wave)
#define NClB (NTOK / TPB)          // 256 cluster blocks
#define RSTRIDE 97                 // member-row LDS stride in float4 (pad 96->97)

__device__ __forceinline__ float dot4(const float4& a, const float4& b) {
    return a.x * b.x + a.y * b.y + a.z * b.z + a.w * b.w;
}

// ---------- K1: bucket tokens by target cluster (1 block, 256 threads) ----------
// wsI layout: [0..256] bucket offsets (exclusive scan, [256]=NTOK), [257..257+NTOK) token list
__global__ __launch_bounds__(256) void hs_meta(
    const int* __restrict__ targets, const int* __restrict__ cluster_assign,
    int* __restrict__ wsI)
{
    __shared__ int cnt[NUM_CLUSTERS];
    __shared__ int scan[NUM_CLUSTERS];
    __shared__ int cur[NUM_CLUSTERS];
    const int tid = threadIdx.x;
    cnt[tid] = 0; cur[tid] = 0;
    __syncthreads();
    int tcv[NTOK / 256];
    #pragma unroll
    for (int i = 0; i < NTOK / 256; ++i) {
        const int t = i * 256 + tid;
        const int tc = cluster_assign[targets[t]];
        tcv[i] = tc;
        atomicAdd(&cnt[tc], 1);
    }
    __syncthreads();
    scan[tid] = cnt[tid];
    __syncthreads();
    for (int d = 1; d < 256; d <<= 1) {      // inclusive Hillis-Steele scan
        const int v = (tid >= d) ? scan[tid - d] : 0;
        __syncthreads();
        scan[tid] += v;
        __syncthreads();
    }
    wsI[tid] = scan[tid] - cnt[tid];         // exclusive offset
    if (tid == 255) wsI[256] = NTOK;
    __syncthreads();
    #pragma unroll
    for (int i = 0; i < NTOK / 256; ++i) {
        const int t = i * 256 + tid;
        const int tc = tcv[i];
        const int p = atomicAdd(&cur[tc], 1);
        wsI[257 + (scan[tc] - cnt[tc]) + p] = t;
    }
}

// ---------- K2: cluster logits/softmax (256 blocks, 16 tokens each) ----------
__global__ __launch_bounds__(256) void hs_cluster(
    const float* __restrict__ hidden,
    const float* __restrict__ cluster_emb,
    const float* __restrict__ item_mask,
    const int*   __restrict__ targets,
    const int*   __restrict__ cluster_assign,
    float* __restrict__ ws)
{
    const int cb   = blockIdx.x;          // 0..255
    const int tid  = threadIdx.x;
    const int t0   = cb * TPB;
    const int lane = tid & 63;
    const int wid  = tid >> 6;
    const int q    = lane >> 4;           // row subgroup 0..3
    const int r    = lane & 15;           // lane within 16-lane D-split

    __shared__ float clog[TPB][NUM_CLUSTERS];   // 16 KB

    const int tw = t0 + wid * 4;
    const float4* h4 = reinterpret_cast<const float4*>(hidden);
    float4 hf[4][6];
    #pragma unroll
    for (int j = 0; j < 4; ++j)
        #pragma unroll
        for (int i = 0; i < 6; ++i)
            hf[j][i] = h4[(size_t)(tw + j) * D4 + i * 16 + r];   // coalesced 256B/i

    const float4* ce4 = reinterpret_cast<const float4*>(cluster_emb);
    #pragma unroll 2
    for (int it = 0; it < 64; ++it) {
        const int c = it * 4 + q;
        float4 ce[6];
        #pragma unroll
        for (int i = 0; i < 6; ++i) ce[i] = ce4[(size_t)c * D4 + i * 16 + r];
        float a0 = 0.f, a1 = 0.f, a2 = 0.f, a3 = 0.f;
        #pragma unroll
        for (int i = 0; i < 6; ++i) {
            a0 += dot4(ce[i], hf[0][i]);
            a1 += dot4(ce[i], hf[1][i]);
            a2 += dot4(ce[i], hf[2][i]);
            a3 += dot4(ce[i], hf[3][i]);
        }
        // fold 4 accumulators over 16 lanes: 5 shuffles total
        const bool hi8 = (r & 8) != 0;
        float u  = hi8 ? a1 : a0;
        float uS = hi8 ? a0 : a1;
        u += __shfl_xor(uS, 8);
        float w  = hi8 ? a3 : a2;
        float wS = hi8 ? a2 : a3;
        w += __shfl_xor(wS, 8);
        const bool hi4 = (r & 4) != 0;
        float zv = hi4 ? w : u;
        float zS = hi4 ? u : w;
        zv += __shfl_xor(zS, 4);
        zv += __shfl_xor(zv, 2);
        zv += __shfl_xor(zv, 1);
        if ((r & 3) == 0) {
            const int m = (r >> 2) & 3;               // class -> token {0,2,1,3}
            const int tokj = (m == 1) ? 2 : (m == 2) ? 1 : m;
            clog[wid * 4 + tokj][c] = zv;
        }
    }

    // ---- wave-local softmax + argmax for this wave's 4 tokens ----
    #pragma unroll
    for (int p = 0; p < 4; ++p) {
        const int t  = wid * 4 + p;
        const int gt = t0 + t;
        const float v0 = clog[t][lane];
        const float v1 = clog[t][lane + 64];
        const float v2 = clog[t][lane + 128];
        const float v3 = clog[t][lane + 192];
        float bv = v0; int bi = lane;
        if (v1 > bv) { bv = v1; bi = lane + 64;  }
        if (v2 > bv) { bv = v2; bi = lane + 128; }
        if (v3 > bv) { bv = v3; bi = lane + 192; }
        #pragma unroll
        for (int m = 32; m > 0; m >>= 1) {
            const float ov = __shfl_xor(bv, m);
            const int   oi = __shfl_xor(bi, m);
            if (ov > bv || (ov == bv && oi < bi)) { bv = ov; bi = oi; }
        }
        float e = expf(v0 - bv) + expf(v1 - bv) + expf(v2 - bv) + expf(v3 - bv);
        #pragma unroll
        for (int m = 32; m > 0; m >>= 1) e += __shfl_xor(e, m);
        const float lse = bv + logf(e);
        if (lane == 0) {
            const int tc = cluster_assign[targets[gt]];
            ws[NTOK + gt]     = item_mask[gt];
            ws[2 * NTOK + gt] = clog[t][tc] - lse;
            ws[4 * NTOK + gt] = (bi == tc) ? 1.f : 0.f;
        }
    }
}

// ---------- K3: member logits, bucketed by cluster (256 blocks) ----------
__global__ __launch_bounds__(256) void hs_member(
    const float* __restrict__ hidden,
    const float* __restrict__ item_emb,
    const int*   __restrict__ targets,
    const int*   __restrict__ in_cluster_id,
    const int*   __restrict__ cluster_idx,
    const int*   __restrict__ wsI,
    float* __restrict__ ws)
{
    const int c    = blockIdx.x;
    const int tid  = threadIdx.x;
    const int lane = tid & 63;
    const int wid  = tid >> 6;

    __shared__ float4 rows[64 * RSTRIDE];   // 99.3 KB, XOR-swizzled
    __shared__ int    ids[64];

    const int off  = wsI[c];
    const int cntc = wsI[c + 1] - off;
    if (cntc == 0) return;

    if (tid < 64) ids[tid] = cluster_idx[c * MCS + tid];
    __syncthreads();

    const float4* ie4 = reinterpret_cast<const float4*>(item_emb);
    for (int j = tid; j < 64 * D4; j += 256) {
        const int s = j / D4, col = j % D4;
        const int id = ids[s];
        float4 v; v.x = v.y = v.z = v.w = 0.f;
        if (id >= 0) v = ie4[(size_t)id * D4 + col];
        rows[s * RSTRIDE + (col ^ ((s >> 3) & 7))] = v;
    }
    __syncthreads();

    const int  swz   = (lane >> 3) & 7;
    const bool valid = ids[lane] >= 0;      // lane owns slot=lane (slots 64..127 are -1)
    const int* list  = wsI + 257;

    for (int i = wid * 2; i < cntc; i += 8) {
        const int tokA  = __builtin_amdgcn_readfirstlane(list[off + i]);
        const bool hasB = (i + 1) < cntc;
        const int tokB  = hasB ? __builtin_amdgcn_readfirstlane(list[off + i + 1]) : tokA;
        const float4* hA = reinterpret_cast<const float4*>(hidden + (size_t)tokA * Ddim);
        const float4* hB = reinterpret_cast<const float4*>(hidden + (size_t)tokB * Ddim);
        float accA = 0.f, accB = 0.f;
        #pragma unroll 8
        for (int k = 0; k < D4; ++k) {
            const float4 rv = rows[lane * RSTRIDE + (k ^ swz)];
            accA += dot4(rv, hA[k]);        // hA[k] uniform -> scalar load
            accB += dot4(rv, hB[k]);
        }
        const float mA = valid ? accA : NEG_INF_F;
        const float mB = valid ? accB : NEG_INF_F;
        float mxA = mA, mxB = mB;
        #pragma unroll
        for (int m = 32; m > 0; m >>= 1) {
            mxA = fmaxf(mxA, __shfl_xor(mxA, m));
            mxB = fmaxf(mxB, __shfl_xor(mxB, m));
        }
        float eA = valid ? expf(mA - mxA) : 0.f;
        float eB = valid ? expf(mB - mxB) : 0.f;
        #pragma unroll
        for (int m = 32; m > 0; m >>= 1) {
            eA += __shfl_xor(eA, m);
            eB += __shfl_xor(eB, m);
        }
        const int tpA = in_cluster_id[targets[tokA]];
        const int tpB = in_cluster_id[targets[tokB]];
        const float vA = __shfl(mA, tpA);
        const float vB = __shfl(mB, tpB);
        if (lane == 0) {
            ws[3 * NTOK + tokA] = vA - (mxA + logf(eA));
            if (hasB) ws[3 * NTOK + tokB] = vB - (mxB + logf(eB));
        }
    }
}

// ---------- K4: deterministic final reduction ----------
__global__ __launch_bounds__(1024) void hs_final(
    const float* __restrict__ ws, float* __restrict__ out)
{
    __shared__ double red[5][1024];
    const int tid = threadIdx.x;
    double a0 = 0, a1 = 0, a2 = 0, a3 = 0, a4 = 0;
    for (int i = tid; i < NTOK; i += 1024) {
        const float msk  = ws[NTOK + i];
        const float tlpc = ws[2 * NTOK + i];
        const float tlpi = ws[3 * NTOK + i];
        a0 += (double)(-(tlpc + tlpi) * msk);
        a1 += (double)msk;
        a2 += (double)tlpc;
        a3 += (double)tlpi;
        a4 += (double)ws[4 * NTOK + i];
    }
    red[0][tid] = a0; red[1][tid] = a1; red[2][tid] = a2;
    red[3][tid] = a3; red[4][tid] = a4;
    __syncthreads();
    for (int s2 = 512; s2 > 0; s2 >>= 1) {
        if (tid < s2) {
            red[0][tid] += red[0][tid + s2];
            red[1][tid] += red[1][tid + s2];
            red[2][tid] += red[2][tid + s2];
            red[3][tid] += red[3][tid + s2];
            red[4][tid] += red[4][tid + s2];
        }
        __syncthreads();
    }
    if (tid == 0) {
        out[0] = (float)(red[0][0] / (red[1][0] + 1e-8));
        out[1] = (float)(-red[2][0] / (double)NTOK);
        out[2] = (float)(-red[3][0] / (double)NTOK);
        out[3] = (float)(red[4][0] / (double)NTOK);
    }
}

extern "C" void kernel_launch(void* const* d_in, const int* in_sizes, int n_in,
                              void* d_out, int out_size, void* d_ws, size_t ws_size,
                              hipStream_t stream) {
    const float* hidden         = (const float*)d_in[0];
    const float* item_emb       = (const float*)d_in[1];
    const float* cluster_emb    = (const float*)d_in[2];
    const float* item_mask      = (const float*)d_in[3];
    const int*   targets        = (const int*)d_in[4];
    const int*   cluster_assign = (const int*)d_in[5];
    const int*   cluster_idx    = (const int*)d_in[6];
    const int*   in_cluster_id  = (const int*)d_in[7];

    float* out = (float*)d_out;
    float* ws  = (float*)d_ws;
    int*   wsI = (int*)(ws + 5 * NTOK);

    const size_t dummy_elems = (size_t)NTOK * NUM_ITEMS; // 67,108,864 zeros

    // Driver fill path measured ~9.6 TB/s in R1 (vs ~2.2 TB/s for our nt-store
    // fill blocks in R4/R5) -> serialize it, drop in-grid fill entirely.
    hipMemsetAsync(d_out, 0, dummy_elems * sizeof(float), stream);

    hs_meta<<<1, 256, 0, stream>>>(targets, cluster_assign, wsI);
    hs_cluster<<<NClB, 256, 0, stream>>>(
        hidden, cluster_emb, item_mask, targets, cluster_assign, ws);
    hs_member<<<NUM_CLUSTERS, 256, 0, stream>>>(
        hidden, item_emb, targets, in_cluster_id, cluster_idx, wsI, ws);
    hs_final<<<1, 1024, 0, stream>>>(ws, out + dummy_elems);
}

// Round 7
// 127.337 us; speedup vs baseline: 1.2147x; 1.2147x over previous
//
#include <hip/hip_runtime.h>
#include <math.h>

#define Ddim 384
#define D4 96                      // Ddim/4
#define NUM_ITEMS 16384
#define NUM_CLUSTERS 256
#define MCS 128                    // MAX_CLUSTER_SIZE
#define NEG_INF_F (-1e9f)
#define NTOK 4096
#define TPB 16                     // tokens per cluster block (4 per wave)
#define NClB (NTOK / TPB)          // 256 cluster blocks
#define NFB 512                    // fill blocks
#define FILL_F4 32768              // float4s per fill block (512 KB)
#define RSTRIDE 97                 // member-row LDS stride in float4 (pad 96->97)

__device__ __forceinline__ float dot4(const float4& a, const float4& b) {
    return a.x * b.x + a.y * b.y + a.z * b.z + a.w * b.w;
}

// One grid: bids 0..767 -> fill (bid%3!=2) / cluster (bid%3==2); bid 768 -> meta.
// Fill uses PLAIN cached stores (nt-stores and SDMA memset both measured ~2.3-2.6
// TB/s; the rocclr fill kernel with plain dwordx4 stores sustains 6.5-7 TB/s).
__global__ __launch_bounds__(256) void hs_fused(
    const float* __restrict__ hidden,
    const float* __restrict__ cluster_emb,
    const float* __restrict__ item_mask,
    const int*   __restrict__ targets,
    const int*   __restrict__ cluster_assign,
    float* __restrict__ dummy_out,
    float* __restrict__ ws,
    int*   __restrict__ wsI)
{
    const int bid = blockIdx.x;
    const int tid = threadIdx.x;

    __shared__ float clog[TPB][NUM_CLUSTERS];   // 16 KB (cluster path)
    __shared__ int   cnt[NUM_CLUSTERS];         // meta path
    __shared__ int   scan[NUM_CLUSTERS];
    __shared__ int   cur[NUM_CLUSTERS];

    if (bid == NFB + NClB) {
        // ---------------- meta block: bucket tokens by target cluster ----------------
        cnt[tid] = 0; cur[tid] = 0;
        __syncthreads();
        int tcv[NTOK / 256];
        #pragma unroll
        for (int i = 0; i < NTOK / 256; ++i) {
            const int t = i * 256 + tid;
            const int tc = cluster_assign[targets[t]];
            tcv[i] = tc;
            atomicAdd(&cnt[tc], 1);
        }
        __syncthreads();
        scan[tid] = cnt[tid];
        __syncthreads();
        for (int d = 1; d < 256; d <<= 1) {      // inclusive Hillis-Steele scan
            const int v = (tid >= d) ? scan[tid - d] : 0;
            __syncthreads();
            scan[tid] += v;
            __syncthreads();
        }
        wsI[tid] = scan[tid] - cnt[tid];         // exclusive offset
        if (tid == 255) wsI[256] = NTOK;
        __syncthreads();
        #pragma unroll
        for (int i = 0; i < NTOK / 256; ++i) {
            const int t = i * 256 + tid;
            const int tc = tcv[i];
            const int p = atomicAdd(&cur[tc], 1);
            wsI[257 + (scan[tc] - cnt[tc]) + p] = t;
        }
        return;
    }

    if (bid % 3 != 2) {
        // ---------------- fill block: zero 512 KB with plain stores ----------------
        const int fid = (bid / 3) * 2 + (bid % 3);
        float4 z; z.x = z.y = z.z = z.w = 0.f;
        float4* o4 = reinterpret_cast<float4*>(dummy_out)
                     + (size_t)fid * FILL_F4 + tid;
        #pragma unroll 8
        for (int i = 0; i < FILL_F4 / 256; ++i)
            o4[(size_t)i * 256] = z;
        return;
    }

    // ---------------- cluster block: 16 tokens (4 per wave, in registers) ----------------
    const int cb   = bid / 3;             // 0..255
    const int t0   = cb * TPB;
    const int lane = tid & 63;
    const int wid  = tid >> 6;
    const int q    = lane >> 4;           // cluster subgroup 0..3
    const int r    = lane & 15;           // lane within 16-lane D-split

    const int tw = t0 + wid * 4;
    const float4* h4 = reinterpret_cast<const float4*>(hidden);
    float4 hf[4][6];
    #pragma unroll
    for (int j = 0; j < 4; ++j)
        #pragma unroll
        for (int i = 0; i < 6; ++i)
            hf[j][i] = h4[(size_t)(tw + j) * D4 + i * 16 + r];   // coalesced 256B/i

    const float4* ce4 = reinterpret_cast<const float4*>(cluster_emb);
    #pragma unroll 2
    for (int it = 0; it < 64; ++it) {
        const int c = it * 4 + q;
        float4 ce[6];
        #pragma unroll
        for (int i = 0; i < 6; ++i) ce[i] = ce4[(size_t)c * D4 + i * 16 + r];
        float a0 = 0.f, a1 = 0.f, a2 = 0.f, a3 = 0.f;
        #pragma unroll
        for (int i = 0; i < 6; ++i) {
            a0 += dot4(ce[i], hf[0][i]);
            a1 += dot4(ce[i], hf[1][i]);
            a2 += dot4(ce[i], hf[2][i]);
            a3 += dot4(ce[i], hf[3][i]);
        }
        // fold 4 accumulators over 16 lanes: 5 shuffles total
        const bool hi8 = (r & 8) != 0;
        float u  = hi8 ? a1 : a0;
        float uS = hi8 ? a0 : a1;
        u += __shfl_xor(uS, 8);
        float w  = hi8 ? a3 : a2;
        float wS = hi8 ? a2 : a3;
        w += __shfl_xor(wS, 8);
        const bool hi4 = (r & 4) != 0;
        float zv = hi4 ? w : u;
        float zS = hi4 ? u : w;
        zv += __shfl_xor(zS, 4);
        zv += __shfl_xor(zv, 2);
        zv += __shfl_xor(zv, 1);
        if ((r & 3) == 0) {
            const int m = (r >> 2) & 3;               // class -> token {0,2,1,3}
            const int tokj = (m == 1) ? 2 : (m == 2) ? 1 : m;
            clog[wid * 4 + tokj][c] = zv;
        }
    }

    // ---- wave-local softmax + argmax (first-index tiebreak) for 4 tokens ----
    #pragma unroll
    for (int p = 0; p < 4; ++p) {
        const int t  = wid * 4 + p;
        const int gt = t0 + t;
        const float v0 = clog[t][lane];
        const float v1 = clog[t][lane + 64];
        const float v2 = clog[t][lane + 128];
        const float v3 = clog[t][lane + 192];
        float bv = v0; int bi = lane;
        if (v1 > bv) { bv = v1; bi = lane + 64;  }
        if (v2 > bv) { bv = v2; bi = lane + 128; }
        if (v3 > bv) { bv = v3; bi = lane + 192; }
        #pragma unroll
        for (int m = 32; m > 0; m >>= 1) {
            const float ov = __shfl_xor(bv, m);
            const int   oi = __shfl_xor(bi, m);
            if (ov > bv || (ov == bv && oi < bi)) { bv = ov; bi = oi; }
        }
        float e = expf(v0 - bv) + expf(v1 - bv) + expf(v2 - bv) + expf(v3 - bv);
        #pragma unroll
        for (int m = 32; m > 0; m >>= 1) e += __shfl_xor(e, m);
        const float lse = bv + logf(e);
        if (lane == 0) {
            const int tc = cluster_assign[targets[gt]];
            ws[NTOK + gt]     = item_mask[gt];
            ws[2 * NTOK + gt] = clog[t][tc] - lse;
            ws[4 * NTOK + gt] = (bi == tc) ? 1.f : 0.f;
        }
    }
}

// ---------- K2: member logits, bucketed by cluster (256 blocks) ----------
__global__ __launch_bounds__(256) void hs_member(
    const float* __restrict__ hidden,
    const float* __restrict__ item_emb,
    const int*   __restrict__ targets,
    const int*   __restrict__ in_cluster_id,
    const int*   __restrict__ cluster_idx,
    const int*   __restrict__ wsI,
    float* __restrict__ ws)
{
    const int c    = blockIdx.x;
    const int tid  = threadIdx.x;
    const int lane = tid & 63;
    const int wid  = tid >> 6;

    __shared__ float4 rows[64 * RSTRIDE];   // 99.3 KB, XOR-swizzled
    __shared__ int    ids[64];

    const int off  = wsI[c];
    const int cntc = wsI[c + 1] - off;
    if (cntc == 0) return;

    if (tid < 64) ids[tid] = cluster_idx[c * MCS + tid];
    __syncthreads();

    const float4* ie4 = reinterpret_cast<const float4*>(item_emb);
    for (int j = tid; j < 64 * D4; j += 256) {
        const int s = j / D4, col = j % D4;
        const int id = ids[s];
        float4 v; v.x = v.y = v.z = v.w = 0.f;
        if (id >= 0) v = ie4[(size_t)id * D4 + col];
        rows[s * RSTRIDE + (col ^ ((s >> 3) & 7))] = v;
    }
    __syncthreads();

    const int  swz   = (lane >> 3) & 7;
    const bool valid = ids[lane] >= 0;      // lane owns slot=lane (slots 64..127 are -1)
    const int* list  = wsI + 257;

    for (int i = wid * 2; i < cntc; i += 8) {
        const int tokA  = __builtin_amdgcn_readfirstlane(list[off + i]);
        const bool hasB = (i + 1) < cntc;
        const int tokB  = hasB ? __builtin_amdgcn_readfirstlane(list[off + i + 1]) : tokA;
        const float4* hA = reinterpret_cast<const float4*>(hidden + (size_t)tokA * Ddim);
        const float4* hB = reinterpret_cast<const float4*>(hidden + (size_t)tokB * Ddim);
        float accA = 0.f, accB = 0.f;
        #pragma unroll 8
        for (int k = 0; k < D4; ++k) {
            const float4 rv = rows[lane * RSTRIDE + (k ^ swz)];
            accA += dot4(rv, hA[k]);        // hA[k] uniform -> scalar load
            accB += dot4(rv, hB[k]);
        }
        const float mA = valid ? accA : NEG_INF_F;
        const float mB = valid ? accB : NEG_INF_F;
        float mxA = mA, mxB = mB;
        #pragma unroll
        for (int m = 32; m > 0; m >>= 1) {
            mxA = fmaxf(mxA, __shfl_xor(mxA, m));
            mxB = fmaxf(mxB, __shfl_xor(mxB, m));
        }
        float eA = valid ? expf(mA - mxA) : 0.f;
        float eB = valid ? expf(mB - mxB) : 0.f;
        #pragma unroll
        for (int m = 32; m > 0; m >>= 1) {
            eA += __shfl_xor(eA, m);
            eB += __shfl_xor(eB, m);
        }
        const int tpA = in_cluster_id[targets[tokA]];
        const int tpB = in_cluster_id[targets[tokB]];
        const float vA = __shfl(mA, tpA);
        const float vB = __shfl(mB, tpB);
        if (lane == 0) {
            ws[3 * NTOK + tokA] = vA - (mxA + logf(eA));
            if (hasB) ws[3 * NTOK + tokB] = vB - (mxB + logf(eB));
        }
    }
}

// ---------- K3: deterministic final reduction ----------
__global__ __launch_bounds__(1024) void hs_final(
    const float* __restrict__ ws, float* __restrict__ out)
{
    __shared__ double red[5][1024];
    const int tid = threadIdx.x;
    double a0 = 0, a1 = 0, a2 = 0, a3 = 0, a4 = 0;
    for (int i = tid; i < NTOK; i += 1024) {
        const float msk  = ws[NTOK + i];
        const float tlpc = ws[2 * NTOK + i];
        const float tlpi = ws[3 * NTOK + i];
        a0 += (double)(-(tlpc + tlpi) * msk);
        a1 += (double)msk;
        a2 += (double)tlpc;
        a3 += (double)tlpi;
        a4 += (double)ws[4 * NTOK + i];
    }
    red[0][tid] = a0; red[1][tid] = a1; red[2][tid] = a2;
    red[3][tid] = a3; red[4][tid] = a4;
    __syncthreads();
    for (int s2 = 512; s2 > 0; s2 >>= 1) {
        if (tid < s2) {
            red[0][tid] += red[0][tid + s2];
            red[1][tid] += red[1][tid + s2];
            red[2][tid] += red[2][tid + s2];
            red[3][tid] += red[3][tid + s2];
            red[4][tid] += red[4][tid + s2];
        }
        __syncthreads();
    }
    if (tid == 0) {
        out[0] = (float)(red[0][0] / (red[1][0] + 1e-8));
        out[1] = (float)(-red[2][0] / (double)NTOK);
        out[2] = (float)(-red[3][0] / (double)NTOK);
        out[3] = (float)(red[4][0] / (double)NTOK);
    }
}

extern "C" void kernel_launch(void* const* d_in, const int* in_sizes, int n_in,
                              void* d_out, int out_size, void* d_ws, size_t ws_size,
                              hipStream_t stream) {
    const float* hidden         = (const float*)d_in[0];
    const float* item_emb       = (const float*)d_in[1];
    const float* cluster_emb    = (const float*)d_in[2];
    const float* item_mask      = (const float*)d_in[3];
    const int*   targets        = (const int*)d_in[4];
    const int*   cluster_assign = (const int*)d_in[5];
    const int*   cluster_idx    = (const int*)d_in[6];
    const int*   in_cluster_id  = (const int*)d_in[7];

    float* out = (float*)d_out;
    float* ws  = (float*)d_ws;
    int*   wsI = (int*)(ws + 5 * NTOK);

    const size_t dummy_elems = (size_t)NTOK * NUM_ITEMS; // 67,108,864 zeros

    hs_fused<<<NFB + NClB + 1, 256, 0, stream>>>(
        hidden, cluster_emb, item_mask, targets, cluster_assign, out, ws, wsI);
    hs_member<<<NUM_CLUSTERS, 256, 0, stream>>>(
        hidden, item_emb, targets, in_cluster_id, cluster_idx, wsI, ws);
    hs_final<<<1, 1024, 0, stream>>>(ws, out + dummy_elems);
}